// Round 3
// baseline (44.514 us; speedup 1.0000x reference)
//
#include <hip/hip_runtime.h>
#include <hip/hip_bf16.h>

#define CORR_STRENGTH 0.1f
#define ERR_THRESH2 1e-12f   // (1e-6)^2 : norm(s) > 1e-6  <=>  |s|^2 > 1e-12

// Native clang vector type: __builtin_nontemporal_store requires a pointer to
// scalar or native vector, not HIP_vector_type<float,4>.
typedef float floatx4 __attribute__((ext_vector_type(4)));

__global__ void __launch_bounds__(256) qec_kernel(
    const float* __restrict__ params,
    const float* __restrict__ Wsyn,   // [3][3]
    const float* __restrict__ bsyn,   // [3]
    const float* __restrict__ Wcorr,  // [3][3][3]
    const float* __restrict__ bcorr,  // [3][3]
    float* __restrict__ out,
    long long nvec,                   // number of 12-float (4-block) chunks
    long long nblk)                   // total number of 3-float blocks
{
    // Load tiny weights once per thread; uniform addresses -> cached broadcast.
    float ws[9], bs[3], wc[27], bc[9];
#pragma unroll
    for (int i = 0; i < 9; ++i)  ws[i] = Wsyn[i];
#pragma unroll
    for (int i = 0; i < 3; ++i)  bs[i] = bsyn[i];
#pragma unroll
    for (int i = 0; i < 27; ++i) wc[i] = Wcorr[i];
#pragma unroll
    for (int i = 0; i < 9; ++i)  bc[i] = bcorr[i];

    const long long tid     = (long long)blockIdx.x * blockDim.x + threadIdx.x;
    const long long nthread = (long long)gridDim.x * blockDim.x;

    // Main path: 4 blocks (12 floats) per iteration via 3x float4.
    const floatx4* __restrict__ src4 = reinterpret_cast<const floatx4*>(params);
    floatx4* __restrict__       dst4 = reinterpret_cast<floatx4*>(out);

    for (long long idx = tid; idx < nvec; idx += nthread) {
        floatx4 a = src4[idx * 3 + 0];
        floatx4 b = src4[idx * 3 + 1];
        floatx4 c = src4[idx * 3 + 2];

        float x[12] = { a.x, a.y, a.z, a.w,
                        b.x, b.y, b.z, b.w,
                        c.x, c.y, c.z, c.w };
        float y[12];

#pragma unroll
        for (int bl = 0; bl < 4; ++bl) {
            const float x0 = x[bl * 3 + 0];
            const float x1 = x[bl * 3 + 1];
            const float x2 = x[bl * 3 + 2];

            // syndromes: s[k] = Wsyn[k][:] . x + bsyn[k]
            float s[3];
#pragma unroll
            for (int k = 0; k < 3; ++k)
                s[k] = fmaf(ws[k * 3 + 0], x0,
                        fmaf(ws[k * 3 + 1], x1,
                         fmaf(ws[k * 3 + 2], x2, bs[k])));

            const float mag2 = s[0] * s[0] + s[1] * s[1] + s[2] * s[2];
            const bool active = mag2 > ERR_THRESH2;

            // correction[k] = sum_j s[j] * (Wcorr[j][k][:] . x + bcorr[j][k])
            float corr[3] = {0.f, 0.f, 0.f};
#pragma unroll
            for (int j = 0; j < 3; ++j) {
#pragma unroll
                for (int k = 0; k < 3; ++k) {
                    const float co = fmaf(wc[j * 9 + k * 3 + 0], x0,
                                      fmaf(wc[j * 9 + k * 3 + 1], x1,
                                       fmaf(wc[j * 9 + k * 3 + 2], x2, bc[j * 3 + k])));
                    corr[k] = fmaf(s[j], co, corr[k]);
                }
            }

#pragma unroll
            for (int k = 0; k < 3; ++k) {
                const float xv = x[bl * 3 + k];
                y[bl * 3 + k] = active ? (xv - CORR_STRENGTH * corr[k]) : xv;
            }
        }

        // Non-temporal stores: output is write-once, never re-read.
        // Early-evict hint keeps the (re-read across graph replays) input
        // resident in L2/L3 instead of being displaced by the output stream.
        floatx4 o0 = { y[0], y[1], y[2],  y[3]  };
        floatx4 o1 = { y[4], y[5], y[6],  y[7]  };
        floatx4 o2 = { y[8], y[9], y[10], y[11] };
        __builtin_nontemporal_store(o0, &dst4[idx * 3 + 0]);
        __builtin_nontemporal_store(o1, &dst4[idx * 3 + 1]);
        __builtin_nontemporal_store(o2, &dst4[idx * 3 + 2]);
    }

    // Tail: any leftover 3-float blocks beyond nvec*4 (scalar path).
    const long long firstTailBlk = nvec * 4;
    for (long long blk = firstTailBlk + tid; blk < nblk; blk += nthread) {
        const float x0 = params[blk * 3 + 0];
        const float x1 = params[blk * 3 + 1];
        const float x2 = params[blk * 3 + 2];

        float s[3];
#pragma unroll
        for (int k = 0; k < 3; ++k)
            s[k] = fmaf(ws[k * 3 + 0], x0,
                    fmaf(ws[k * 3 + 1], x1,
                     fmaf(ws[k * 3 + 2], x2, bs[k])));

        const float mag2 = s[0] * s[0] + s[1] * s[1] + s[2] * s[2];
        const bool active = mag2 > ERR_THRESH2;

        float corr[3] = {0.f, 0.f, 0.f};
#pragma unroll
        for (int j = 0; j < 3; ++j) {
#pragma unroll
            for (int k = 0; k < 3; ++k) {
                const float co = fmaf(wc[j * 9 + k * 3 + 0], x0,
                                  fmaf(wc[j * 9 + k * 3 + 1], x1,
                                   fmaf(wc[j * 9 + k * 3 + 2], x2, bc[j * 3 + k])));
                corr[k] = fmaf(s[j], co, corr[k]);
            }
        }

        out[blk * 3 + 0] = active ? (x0 - CORR_STRENGTH * corr[0]) : x0;
        out[blk * 3 + 1] = active ? (x1 - CORR_STRENGTH * corr[1]) : x1;
        out[blk * 3 + 2] = active ? (x2 - CORR_STRENGTH * corr[2]) : x2;
    }
}

extern "C" void kernel_launch(void* const* d_in, const int* in_sizes, int n_in,
                              void* d_out, int out_size, void* d_ws, size_t ws_size,
                              hipStream_t stream) {
    const float* params = (const float*)d_in[0];
    const float* Wsyn   = (const float*)d_in[1];
    const float* bsyn   = (const float*)d_in[2];
    const float* Wcorr  = (const float*)d_in[3];
    const float* bcorr  = (const float*)d_in[4];
    float* out = (float*)d_out;

    const long long n    = (long long)in_sizes[0];  // total elements (divisible by 3 here)
    const long long nblk = n / 3;                   // 3-float blocks
    const long long nvec = n / 12;                  // 12-float (4-block) vector chunks

    const int block = 256;
    const int grid  = 2048;  // 256 CUs x 8 blocks; grid-stride covers the rest

    qec_kernel<<<grid, block, 0, stream>>>(params, Wsyn, bsyn, Wcorr, bcorr,
                                           out, nvec, nblk);
}

// Round 4
// 38.280 us; speedup vs baseline: 1.1629x; 1.1629x over previous
//
#include <hip/hip_runtime.h>
#include <hip/hip_bf16.h>

#define CORR_STRENGTH 0.1f
#define ERR_THRESH2 1e-12f   // (1e-6)^2 : norm(s) > 1e-6  <=>  |s|^2 > 1e-12

typedef float floatx4 __attribute__((ext_vector_type(4)));

__global__ void __launch_bounds__(256) qec_kernel(
    const float* __restrict__ params,
    const float* __restrict__ Wsyn,   // [3][3]
    const float* __restrict__ bsyn,   // [3]
    const float* __restrict__ Wcorr,  // [3][3][3]
    const float* __restrict__ bcorr,  // [3][3]
    float* __restrict__ out,
    long long nvec,                   // number of 12-float (4-block) chunks
    long long nblk)                   // total number of 3-float blocks
{
    // Load tiny weights once per thread; uniform addresses -> cached broadcast.
    float ws[9], bs[3], wc[27], bc[9];
#pragma unroll
    for (int i = 0; i < 9; ++i)  ws[i] = Wsyn[i];
#pragma unroll
    for (int i = 0; i < 3; ++i)  bs[i] = bsyn[i];
#pragma unroll
    for (int i = 0; i < 27; ++i) wc[i] = Wcorr[i];
#pragma unroll
    for (int i = 0; i < 9; ++i)  bc[i] = bcorr[i];

    const long long tid     = (long long)blockIdx.x * blockDim.x + threadIdx.x;
    const long long nthread = (long long)gridDim.x * blockDim.x;

    const floatx4* __restrict__ src4 = reinterpret_cast<const floatx4*>(params);
    floatx4* __restrict__       dst4 = reinterpret_cast<floatx4*>(out);

    // Grid sized so each thread does exactly one iteration (no loop-carried
    // serialization; maximal memory-level parallelism). Loop kept for safety.
    for (long long idx = tid; idx < nvec; idx += nthread) {
        floatx4 a = src4[idx * 3 + 0];
        floatx4 b = src4[idx * 3 + 1];
        floatx4 c = src4[idx * 3 + 2];

        float x[12] = { a.x, a.y, a.z, a.w,
                        b.x, b.y, b.z, b.w,
                        c.x, c.y, c.z, c.w };
        float y[12];

#pragma unroll
        for (int bl = 0; bl < 4; ++bl) {
            const float x0 = x[bl * 3 + 0];
            const float x1 = x[bl * 3 + 1];
            const float x2 = x[bl * 3 + 2];

            // syndromes: s[k] = Wsyn[k][:] . x + bsyn[k]
            float s[3];
#pragma unroll
            for (int k = 0; k < 3; ++k)
                s[k] = fmaf(ws[k * 3 + 0], x0,
                        fmaf(ws[k * 3 + 1], x1,
                         fmaf(ws[k * 3 + 2], x2, bs[k])));

            const float mag2 = s[0] * s[0] + s[1] * s[1] + s[2] * s[2];
            const bool active = mag2 > ERR_THRESH2;

            // correction[k] = sum_j s[j] * (Wcorr[j][k][:] . x + bcorr[j][k])
            float corr[3] = {0.f, 0.f, 0.f};
#pragma unroll
            for (int j = 0; j < 3; ++j) {
#pragma unroll
                for (int k = 0; k < 3; ++k) {
                    const float co = fmaf(wc[j * 9 + k * 3 + 0], x0,
                                      fmaf(wc[j * 9 + k * 3 + 1], x1,
                                       fmaf(wc[j * 9 + k * 3 + 2], x2, bc[j * 3 + k])));
                    corr[k] = fmaf(s[j], co, corr[k]);
                }
            }

#pragma unroll
            for (int k = 0; k < 3; ++k) {
                const float xv = x[bl * 3 + k];
                y[bl * 3 + k] = active ? (xv - CORR_STRENGTH * corr[k]) : xv;
            }
        }

        floatx4 o0 = { y[0], y[1], y[2],  y[3]  };
        floatx4 o1 = { y[4], y[5], y[6],  y[7]  };
        floatx4 o2 = { y[8], y[9], y[10], y[11] };
        dst4[idx * 3 + 0] = o0;
        dst4[idx * 3 + 1] = o1;
        dst4[idx * 3 + 2] = o2;
    }

    // Tail: any leftover 3-float blocks beyond nvec*4 (scalar path).
    const long long firstTailBlk = nvec * 4;
    for (long long blk = firstTailBlk + tid; blk < nblk; blk += nthread) {
        const float x0 = params[blk * 3 + 0];
        const float x1 = params[blk * 3 + 1];
        const float x2 = params[blk * 3 + 2];

        float s[3];
#pragma unroll
        for (int k = 0; k < 3; ++k)
            s[k] = fmaf(ws[k * 3 + 0], x0,
                    fmaf(ws[k * 3 + 1], x1,
                     fmaf(ws[k * 3 + 2], x2, bs[k])));

        const float mag2 = s[0] * s[0] + s[1] * s[1] + s[2] * s[2];
        const bool active = mag2 > ERR_THRESH2;

        float corr[3] = {0.f, 0.f, 0.f};
#pragma unroll
        for (int j = 0; j < 3; ++j) {
#pragma unroll
            for (int k = 0; k < 3; ++k) {
                const float co = fmaf(wc[j * 9 + k * 3 + 0], x0,
                                  fmaf(wc[j * 9 + k * 3 + 1], x1,
                                   fmaf(wc[j * 9 + k * 3 + 2], x2, bc[j * 3 + k])));
                corr[k] = fmaf(s[j], co, corr[k]);
            }
        }

        out[blk * 3 + 0] = active ? (x0 - CORR_STRENGTH * corr[0]) : x0;
        out[blk * 3 + 1] = active ? (x1 - CORR_STRENGTH * corr[1]) : x1;
        out[blk * 3 + 2] = active ? (x2 - CORR_STRENGTH * corr[2]) : x2;
    }
}

extern "C" void kernel_launch(void* const* d_in, const int* in_sizes, int n_in,
                              void* d_out, int out_size, void* d_ws, size_t ws_size,
                              hipStream_t stream) {
    const float* params = (const float*)d_in[0];
    const float* Wsyn   = (const float*)d_in[1];
    const float* bsyn   = (const float*)d_in[2];
    const float* Wcorr  = (const float*)d_in[3];
    const float* bcorr  = (const float*)d_in[4];
    float* out = (float*)d_out;

    const long long n    = (long long)in_sizes[0];  // total elements (divisible by 3 here)
    const long long nblk = n / 3;                   // 3-float blocks
    const long long nvec = n / 12;                  // 12-float (4-block) vector chunks

    const int block = 256;
    // One iteration per thread: nvec = 2,097,152 -> 8192 blocks of 256.
    long long grid_ll = (nvec + block - 1) / block;
    if (grid_ll < 1) grid_ll = 1;
    if (grid_ll > 65535LL * 64LL) grid_ll = 65535LL * 64LL;  // paranoia clamp
    const int grid = (int)grid_ll;

    qec_kernel<<<grid, block, 0, stream>>>(params, Wsyn, bsyn, Wcorr, bcorr,
                                           out, nvec, nblk);
}

// Round 5
// 38.143 us; speedup vs baseline: 1.1670x; 1.0036x over previous
//
#include <hip/hip_runtime.h>
#include <hip/hip_bf16.h>

#define CORR_STRENGTH 0.1f
#define ERR_THRESH2 1e-12f   // (1e-6)^2 : norm(s) > 1e-6  <=>  |s|^2 > 1e-12

typedef float floatx4 __attribute__((ext_vector_type(4)));

// Computes the QEC update for one 3-float block.
__device__ __forceinline__ void qec_block(
    const float* __restrict__ ws, const float* __restrict__ bs,
    const float* __restrict__ wc, const float* __restrict__ bc,
    float x0, float x1, float x2, float* __restrict__ y)
{
    float s[3];
#pragma unroll
    for (int k = 0; k < 3; ++k)
        s[k] = fmaf(ws[k * 3 + 0], x0,
                fmaf(ws[k * 3 + 1], x1,
                 fmaf(ws[k * 3 + 2], x2, bs[k])));

    const float mag2 = s[0] * s[0] + s[1] * s[1] + s[2] * s[2];
    const bool active = mag2 > ERR_THRESH2;

    float corr[3] = {0.f, 0.f, 0.f};
#pragma unroll
    for (int j = 0; j < 3; ++j) {
#pragma unroll
        for (int k = 0; k < 3; ++k) {
            const float co = fmaf(wc[j * 9 + k * 3 + 0], x0,
                              fmaf(wc[j * 9 + k * 3 + 1], x1,
                               fmaf(wc[j * 9 + k * 3 + 2], x2, bc[j * 3 + k])));
            corr[k] = fmaf(s[j], co, corr[k]);
        }
    }

    y[0] = active ? (x0 - CORR_STRENGTH * corr[0]) : x0;
    y[1] = active ? (x1 - CORR_STRENGTH * corr[1]) : x1;
    y[2] = active ? (x2 - CORR_STRENGTH * corr[2]) : x2;
}

__global__ void __launch_bounds__(256) qec_kernel(
    const float* __restrict__ params,
    const float* __restrict__ Wsyn,   // [3][3]
    const float* __restrict__ bsyn,   // [3]
    const float* __restrict__ Wcorr,  // [3][3][3]
    const float* __restrict__ bcorr,  // [3][3]
    float* __restrict__ out,
    long long nBT,                    // full block-tiles (768 float4 each)
    long long nvec,                   // total 12-float (3-float4) chunks
    long long nblk)                   // total 3-float blocks
{
    // Wave-private staging: 4 waves x 192 float4 (3 KB each).
    __shared__ floatx4 lds[4][192];

    // Tiny weights: uniform addresses -> scalar loads, cached.
    float ws[9], bs[3], wc[27], bc[9];
#pragma unroll
    for (int i = 0; i < 9; ++i)  ws[i] = Wsyn[i];
#pragma unroll
    for (int i = 0; i < 3; ++i)  bs[i] = bsyn[i];
#pragma unroll
    for (int i = 0; i < 27; ++i) wc[i] = Wcorr[i];
#pragma unroll
    for (int i = 0; i < 9; ++i)  bc[i] = bcorr[i];

    const int wave = threadIdx.x >> 6;
    const int lane = threadIdx.x & 63;

    const floatx4* __restrict__ src4 = reinterpret_cast<const floatx4*>(params);
    floatx4* __restrict__       dst4 = reinterpret_cast<floatx4*>(out);

    // ---- Main coalesced path: one block-tile = 768 contiguous float4 ----
    // Per wave: 3 fully-coalesced 1KB loads -> LDS -> per-lane contiguous
    // 48B reads (stride-48B b128 is bank-conflict-free: 8 lanes x 12-bank
    // step cover all 32 banks) -> compute -> reverse permutation -> 3
    // coalesced 1KB stores.
    for (long long bt = blockIdx.x; bt < nBT; bt += gridDim.x) {
        const long long base4 = bt * 768 + (long long)wave * 192;

        floatx4 v0 = src4[base4 +   0 + lane];
        floatx4 v1 = src4[base4 +  64 + lane];
        floatx4 v2 = src4[base4 + 128 + lane];
        lds[wave][  0 + lane] = v0;
        lds[wave][ 64 + lane] = v1;
        lds[wave][128 + lane] = v2;
        __syncthreads();

        floatx4 a = lds[wave][3 * lane + 0];
        floatx4 b = lds[wave][3 * lane + 1];
        floatx4 c = lds[wave][3 * lane + 2];

        float x[12] = { a.x, a.y, a.z, a.w,
                        b.x, b.y, b.z, b.w,
                        c.x, c.y, c.z, c.w };
        float y[12];
#pragma unroll
        for (int bl = 0; bl < 4; ++bl)
            qec_block(ws, bs, wc, bc,
                      x[bl * 3 + 0], x[bl * 3 + 1], x[bl * 3 + 2],
                      &y[bl * 3]);

        floatx4 o0 = { y[0], y[1], y[2],  y[3]  };
        floatx4 o1 = { y[4], y[5], y[6],  y[7]  };
        floatx4 o2 = { y[8], y[9], y[10], y[11] };
        __syncthreads();   // WAR: don't overwrite until all reads done
        lds[wave][3 * lane + 0] = o0;
        lds[wave][3 * lane + 1] = o1;
        lds[wave][3 * lane + 2] = o2;
        __syncthreads();

        floatx4 r0 = lds[wave][  0 + lane];
        floatx4 r1 = lds[wave][ 64 + lane];
        floatx4 r2 = lds[wave][128 + lane];
        dst4[base4 +   0 + lane] = r0;
        dst4[base4 +  64 + lane] = r1;
        dst4[base4 + 128 + lane] = r2;
        __syncthreads();   // WAR before next iteration's stage-in
    }

    // ---- Tail paths (no barriers; remainder only) ----
    const long long tid     = (long long)blockIdx.x * blockDim.x + threadIdx.x;
    const long long nthread = (long long)gridDim.x * blockDim.x;

    // Leftover 12-float chunks beyond the block-tiles (old strided path).
    const long long tailIdx0 = nBT * 256;
    for (long long idx = tailIdx0 + tid; idx < nvec; idx += nthread) {
        floatx4 a = src4[idx * 3 + 0];
        floatx4 b = src4[idx * 3 + 1];
        floatx4 c = src4[idx * 3 + 2];
        float x[12] = { a.x, a.y, a.z, a.w,
                        b.x, b.y, b.z, b.w,
                        c.x, c.y, c.z, c.w };
        float y[12];
#pragma unroll
        for (int bl = 0; bl < 4; ++bl)
            qec_block(ws, bs, wc, bc,
                      x[bl * 3 + 0], x[bl * 3 + 1], x[bl * 3 + 2],
                      &y[bl * 3]);
        dst4[idx * 3 + 0] = floatx4{ y[0], y[1], y[2],  y[3]  };
        dst4[idx * 3 + 1] = floatx4{ y[4], y[5], y[6],  y[7]  };
        dst4[idx * 3 + 2] = floatx4{ y[8], y[9], y[10], y[11] };
    }

    // Leftover 3-float blocks beyond nvec*4 (scalar path).
    const long long firstTailBlk = nvec * 4;
    for (long long blk = firstTailBlk + tid; blk < nblk; blk += nthread) {
        float y[3];
        qec_block(ws, bs, wc, bc,
                  params[blk * 3 + 0], params[blk * 3 + 1], params[blk * 3 + 2], y);
        out[blk * 3 + 0] = y[0];
        out[blk * 3 + 1] = y[1];
        out[blk * 3 + 2] = y[2];
    }
}

extern "C" void kernel_launch(void* const* d_in, const int* in_sizes, int n_in,
                              void* d_out, int out_size, void* d_ws, size_t ws_size,
                              hipStream_t stream) {
    const float* params = (const float*)d_in[0];
    const float* Wsyn   = (const float*)d_in[1];
    const float* bsyn   = (const float*)d_in[2];
    const float* Wcorr  = (const float*)d_in[3];
    const float* bcorr  = (const float*)d_in[4];
    float* out = (float*)d_out;

    const long long n     = (long long)in_sizes[0];  // total elements
    const long long nblk  = n / 3;                   // 3-float blocks
    const long long nvec  = n / 12;                  // 12-float chunks
    const long long nf4   = n / 4;                   // aligned float4 count
    const long long nBT   = nf4 / 768;               // block-tiles (768 f4 each)

    const int block = 256;
    long long grid_ll = nBT > 0 ? nBT : 1;
    if (grid_ll > 16384) grid_ll = 16384;
    const int grid = (int)grid_ll;   // 8192 for the bench shape: 1 tile/block

    qec_kernel<<<grid, block, 0, stream>>>(params, Wsyn, bsyn, Wcorr, bcorr,
                                           out, nBT, nvec, nblk);
}